// Round 1
// baseline (851.116 us; speedup 1.0000x reference)
//
#include <hip/hip_runtime.h>

#define DIMSZ 1024
#define NB 8
#define TSEQ 2048
#define MTOT (NB*TSEQ)   // 16384

typedef __attribute__((ext_vector_type(8))) short short8v;
typedef __attribute__((ext_vector_type(4))) float f32x4;

__device__ __forceinline__ unsigned short f2bf(float f) {
  unsigned int u; __builtin_memcpy(&u, &f, 4);
  unsigned int r = u + 0x7FFF + ((u >> 16) & 1);   // RNE
  return (unsigned short)(r >> 16);
}
__device__ __forceinline__ float bf2f(unsigned short us) {
  unsigned int v = ((unsigned int)us) << 16;
  float f; __builtin_memcpy(&f, &v, 4); return f;
}

// ---------------- cast x (f32) -> bf16, 4 elems/thread ----------------
__global__ __launch_bounds__(256) void cast_x_kernel(
    const float* __restrict__ in, unsigned short* __restrict__ out) {
  int i = blockIdx.x * 256 + threadIdx.x;
  float4 f = reinterpret_cast<const float4*>(in)[i];
  uint2 o;
  o.x = (unsigned)f2bf(f.x) | ((unsigned)f2bf(f.y) << 16);
  o.y = (unsigned)f2bf(f.z) | ((unsigned)f2bf(f.w) << 16);
  reinterpret_cast<uint2*>(out)[i] = o;
}

// ---------------- transpose + cast W [K][N] f32 -> WT [N][K] bf16 ----------------
__global__ __launch_bounds__(256) void transpose_cast_kernel(
    const float* __restrict__ W, unsigned short* __restrict__ WT) {
  __shared__ float tile[32][33];
  int tx = threadIdx.x & 31, ty = threadIdx.x >> 5;   // 32 x 8
  int row0 = blockIdx.y * 32, col0 = blockIdx.x * 32;
  #pragma unroll
  for (int j = 0; j < 32; j += 8)
    tile[ty + j][tx] = W[(size_t)(row0 + ty + j) * DIMSZ + col0 + tx];
  __syncthreads();
  #pragma unroll
  for (int j = 0; j < 32; j += 8)
    WT[(size_t)(col0 + ty + j) * DIMSZ + row0 + tx] = f2bf(tile[tx][ty + j]);
}

// ---------------- bf16 MFMA GEMM: C[M][N] = A[M][K] * BT[N][K]^T + bias ----------------
// 128x128 tile, BK=64, 4 waves in 2x2, each wave 64x64 via 4x4 16x16x32 MFMAs.
#define BM 128
#define BN 128
#define BKK 64
#define LDT 72   // padded LDS row (bf16 elems): 144B stride -> 2-way bank alias (free), 16B aligned

template<int OUTBF>
__global__ __launch_bounds__(256) void gemm_bt_kernel(
    const unsigned short* __restrict__ A,
    const unsigned short* __restrict__ BT,
    void* __restrict__ Cv,
    const float* __restrict__ bias0,
    const float* __restrict__ bias1,
    int M, int N, int K, int Nsplit) {
  __shared__ __align__(16) unsigned short As[BM][LDT];
  __shared__ __align__(16) unsigned short Bs[BN][LDT];
  const int tid  = threadIdx.x;
  const int brow = blockIdx.x * BM;
  const int bcol = blockIdx.y * BN;
  const int wid  = tid >> 6;
  const int lane = tid & 63;
  const int wr = wid >> 1, wc = wid & 1;
  const int lrow = lane & 15;
  const int lko  = (lane >> 4) * 8;

  f32x4 acc[4][4];
  #pragma unroll
  for (int m = 0; m < 4; ++m)
    #pragma unroll
    for (int n = 0; n < 4; ++n)
      acc[m][n] = (f32x4){0.f, 0.f, 0.f, 0.f};

  for (int k0 = 0; k0 < K; k0 += BKK) {
    // stage A and BT tiles: 128 rows x 64 bf16 each = 1024 16B-segments each
    #pragma unroll
    for (int j = 0; j < 4; ++j) {
      int i = j * 256 + tid;        // 0..1023
      int r = i >> 3, s = i & 7;
      *reinterpret_cast<short8v*>(&As[r][s * 8]) =
          *reinterpret_cast<const short8v*>(&A[(size_t)(brow + r) * K + k0 + s * 8]);
      *reinterpret_cast<short8v*>(&Bs[r][s * 8]) =
          *reinterpret_cast<const short8v*>(&BT[(size_t)(bcol + r) * K + k0 + s * 8]);
    }
    __syncthreads();
    #pragma unroll
    for (int kk = 0; kk < BKK; kk += 32) {
      short8v af[4], bf[4];
      #pragma unroll
      for (int m = 0; m < 4; ++m)
        af[m] = *reinterpret_cast<const short8v*>(&As[wr * 64 + m * 16 + lrow][kk + lko]);
      #pragma unroll
      for (int n = 0; n < 4; ++n)
        bf[n] = *reinterpret_cast<const short8v*>(&Bs[wc * 64 + n * 16 + lrow][kk + lko]);
      #pragma unroll
      for (int m = 0; m < 4; ++m)
        #pragma unroll
        for (int n = 0; n < 4; ++n)
          acc[m][n] = __builtin_amdgcn_mfma_f32_16x16x32_bf16(af[m], bf[n], acc[m][n], 0, 0, 0);
    }
    __syncthreads();
  }

  const int orow = brow + wr * 64;
  const int ocol = bcol + wc * 64;
  #pragma unroll
  for (int n = 0; n < 4; ++n) {
    int col = ocol + n * 16 + lrow;
    float b = (col < Nsplit) ? bias0[col] : bias1[col - Nsplit];
    #pragma unroll
    for (int m = 0; m < 4; ++m) {
      #pragma unroll
      for (int r = 0; r < 4; ++r) {
        int row = orow + m * 16 + (lane >> 4) * 4 + r;
        float val = acc[m][n][r] + b;
        if (OUTBF) {
          ((unsigned short*)Cv)[(size_t)row * N + col] = f2bf(val);
        } else {
          ((float*)Cv)[(size_t)row * N + col] = val;
        }
      }
    }
  }
}

// ---------------- WKV recurrence: 8192 channels, serial over T, fp32 ----------------
// kv: bf16 [MTOT][2048], k in cols 0..1023, v in cols 1024..2047 (row = n*T + t)
// O:  bf16 [MTOT][1024]
__global__ __launch_bounds__(64) void wkv_kernel(
    const unsigned short* __restrict__ kv,
    const float* __restrict__ wdec,
    const float* __restrict__ ubon,
    unsigned short* __restrict__ O) {
  int ch = blockIdx.x * 64 + threadIdx.x;   // 0..8191
  int n = ch >> 10, c = ch & 1023;
  float w = wdec[c], u = ubon[c];
  const unsigned short* base = kv + (size_t)n * TSEQ * 2048 + c;
  unsigned short* ob = O + (size_t)n * TSEQ * DIMSZ + c;

  float pp = bf2f(base[0]);
  float aa = bf2f(base[1024]);
  float bb = 1.f;
  ob[0] = base[1024];   // O[0] = v[0]

  float kb[8], vb[8];
  #pragma unroll
  for (int j = 0; j < 8; ++j) {
    kb[j] = bf2f(base[(size_t)(1 + j) * 2048]);
    vb[j] = bf2f(base[(size_t)(1 + j) * 2048 + 1024]);
  }

  for (int t0 = 1; t0 < TSEQ; t0 += 8) {
    float kn[8], vn[8];
    int tn = t0 + 8;
    #pragma unroll
    for (int j = 0; j < 8; ++j) {
      if (tn + j < TSEQ) {
        kn[j] = bf2f(base[(size_t)(tn + j) * 2048]);
        vn[j] = bf2f(base[(size_t)(tn + j) * 2048 + 1024]);
      } else { kn[j] = 0.f; vn[j] = 0.f; }
    }
    #pragma unroll
    for (int j = 0; j < 8; ++j) {
      int t = t0 + j;
      if (t < TSEQ) {
        float kt = kb[j], vt = vb[j];
        // output at t (bonus u), previous state
        float ww = u + kt;
        float qq = fmaxf(ww, pp);
        float e1 = __expf(pp - qq);
        float e2 = __expf(ww - qq);
        float num = e1 * aa + e2 * vt;
        float den = e1 * bb + e2;
        float o = num * __builtin_amdgcn_rcpf(den);
        ob[(size_t)t * DIMSZ] = f2bf(o);
        // state update (decay w)
        float ww2 = pp - w;
        float qq2 = fmaxf(ww2, kt);
        float e1b = __expf(ww2 - qq2);
        float e2b = __expf(kt - qq2);
        aa = e1b * aa + e2b * vt;
        bb = e1b * bb + e2b;
        pp = qq2;
      }
    }
    #pragma unroll
    for (int j = 0; j < 8; ++j) { kb[j] = kn[j]; vb[j] = vn[j]; }
  }
}

extern "C" void kernel_launch(void* const* d_in, const int* in_sizes, int n_in,
                              void* d_out, int out_size, void* d_ws, size_t ws_size,
                              hipStream_t stream) {
  const float* x  = (const float*)d_in[0];
  // d_in[1]=Wq, d_in[2]=bq: unused by the reference forward
  const float* Wk = (const float*)d_in[3];
  const float* bk = (const float*)d_in[4];
  const float* Wv = (const float*)d_in[5];
  const float* bv = (const float*)d_in[6];
  const float* wr = (const float*)d_in[7];
  const float* ur = (const float*)d_in[8];
  const float* Wo = (const float*)d_in[9];
  const float* bo = (const float*)d_in[10];
  float* out = (float*)d_out;

  char* ws = (char*)d_ws;
  unsigned short* xb   = (unsigned short*)(ws);               // 32MB  [16384][1024] bf16 (reused as O)
  unsigned short* WTkv = (unsigned short*)(ws + 33554432);    // 4MB   [2048][1024] bf16 (Wk^T ; Wv^T)
  unsigned short* WoT  = (unsigned short*)(ws + 37748736);    // 2MB   [1024][1024] bf16
  unsigned short* kvb  = (unsigned short*)(ws + 39845888);    // 64MB  [16384][2048] bf16

  cast_x_kernel<<<dim3(16384), dim3(256), 0, stream>>>(x, xb);
  transpose_cast_kernel<<<dim3(32, 32), dim3(256), 0, stream>>>(Wk, WTkv);
  transpose_cast_kernel<<<dim3(32, 32), dim3(256), 0, stream>>>(Wv, WTkv + 1024 * 1024);
  transpose_cast_kernel<<<dim3(32, 32), dim3(256), 0, stream>>>(Wo, WoT);

  // k|v projection: [16384][1024] @ [1024][2048] -> bf16 kv buffer (+bk|bv)
  gemm_bt_kernel<1><<<dim3(128, 16), dim3(256), 0, stream>>>(
      xb, WTkv, (void*)kvb, bk, bv, MTOT, 2048, 1024, 1024);

  // WKV recurrence -> O (bf16), overwrites xb (safe: projection GEMM already consumed it)
  wkv_kernel<<<dim3(128), dim3(64), 0, stream>>>(kvb, wr, ur, xb);

  // output projection: [16384][1024] @ [1024][1024] -> f32 d_out (+bo)
  gemm_bt_kernel<0><<<dim3(128, 8), dim3(256), 0, stream>>>(
      xb, WoT, (void*)out, bo, bo, MTOT, 1024, 1024, 1024);
}

// Round 2
// 204.589 us; speedup vs baseline: 4.1601x; 4.1601x over previous
//
#include <hip/hip_runtime.h>

#define DIMSZ 1024
#define NB 8
#define TSEQ 2048
#define MTOT (NB*TSEQ)   // 16384
#define CCH 64           // chunks per sequence
#define LCH (TSEQ/CCH)   // 32 steps per chunk
#define NCHAN (NB*DIMSZ) // 8192 independent channels

typedef __attribute__((ext_vector_type(8))) short short8v;
typedef __attribute__((ext_vector_type(4))) float f32x4;

__device__ __forceinline__ unsigned short f2bf(float f) {
  unsigned int u; __builtin_memcpy(&u, &f, 4);
  unsigned int r = u + 0x7FFF + ((u >> 16) & 1);   // RNE
  return (unsigned short)(r >> 16);
}
__device__ __forceinline__ float bf2f(unsigned short us) {
  unsigned int v = ((unsigned int)us) << 16;
  float f; __builtin_memcpy(&f, &v, 4); return f;
}

// ---------------- cast x (f32) -> bf16, 4 elems/thread ----------------
__global__ __launch_bounds__(256) void cast_x_kernel(
    const float* __restrict__ in, unsigned short* __restrict__ out) {
  int i = blockIdx.x * 256 + threadIdx.x;
  float4 f = reinterpret_cast<const float4*>(in)[i];
  uint2 o;
  o.x = (unsigned)f2bf(f.x) | ((unsigned)f2bf(f.y) << 16);
  o.y = (unsigned)f2bf(f.z) | ((unsigned)f2bf(f.w) << 16);
  reinterpret_cast<uint2*>(out)[i] = o;
}

// ---------------- transpose + cast W [K][N] f32 -> WT [N][K] bf16 ----------------
__global__ __launch_bounds__(256) void transpose_cast_kernel(
    const float* __restrict__ W, unsigned short* __restrict__ WT) {
  __shared__ float tile[32][33];
  int tx = threadIdx.x & 31, ty = threadIdx.x >> 5;   // 32 x 8
  int row0 = blockIdx.y * 32, col0 = blockIdx.x * 32;
  #pragma unroll
  for (int j = 0; j < 32; j += 8)
    tile[ty + j][tx] = W[(size_t)(row0 + ty + j) * DIMSZ + col0 + tx];
  __syncthreads();
  #pragma unroll
  for (int j = 0; j < 32; j += 8)
    WT[(size_t)(col0 + ty + j) * DIMSZ + row0 + tx] = f2bf(tile[tx][ty + j]);
}

// ---------------- bf16 MFMA GEMM: C[M][N] = A[M][K] * BT[N][K]^T + bias ----------------
// 128x128 tile, BK=64, 4 waves in 2x2, each wave 64x64 via 4x4 16x16x32 MFMAs.
#define BM 128
#define BN 128
#define BKK 64
#define LDT 72   // padded LDS row (bf16 elems): 144B stride -> 2-way bank alias (free), 16B aligned

template<int OUTBF>
__global__ __launch_bounds__(256) void gemm_bt_kernel(
    const unsigned short* __restrict__ A,
    const unsigned short* __restrict__ BT,
    void* __restrict__ Cv,
    const float* __restrict__ bias0,
    const float* __restrict__ bias1,
    int M, int N, int K, int Nsplit) {
  __shared__ __align__(16) unsigned short As[BM][LDT];
  __shared__ __align__(16) unsigned short Bs[BN][LDT];
  const int tid  = threadIdx.x;
  const int brow = blockIdx.x * BM;
  const int bcol = blockIdx.y * BN;
  const int wid  = tid >> 6;
  const int lane = tid & 63;
  const int wr = wid >> 1, wc = wid & 1;
  const int lrow = lane & 15;
  const int lko  = (lane >> 4) * 8;

  f32x4 acc[4][4];
  #pragma unroll
  for (int m = 0; m < 4; ++m)
    #pragma unroll
    for (int n = 0; n < 4; ++n)
      acc[m][n] = (f32x4){0.f, 0.f, 0.f, 0.f};

  for (int k0 = 0; k0 < K; k0 += BKK) {
    #pragma unroll
    for (int j = 0; j < 4; ++j) {
      int i = j * 256 + tid;        // 0..1023
      int r = i >> 3, s = i & 7;
      *reinterpret_cast<short8v*>(&As[r][s * 8]) =
          *reinterpret_cast<const short8v*>(&A[(size_t)(brow + r) * K + k0 + s * 8]);
      *reinterpret_cast<short8v*>(&Bs[r][s * 8]) =
          *reinterpret_cast<const short8v*>(&BT[(size_t)(bcol + r) * K + k0 + s * 8]);
    }
    __syncthreads();
    #pragma unroll
    for (int kk = 0; kk < BKK; kk += 32) {
      short8v af[4], bf[4];
      #pragma unroll
      for (int m = 0; m < 4; ++m)
        af[m] = *reinterpret_cast<const short8v*>(&As[wr * 64 + m * 16 + lrow][kk + lko]);
      #pragma unroll
      for (int n = 0; n < 4; ++n)
        bf[n] = *reinterpret_cast<const short8v*>(&Bs[wc * 64 + n * 16 + lrow][kk + lko]);
      #pragma unroll
      for (int m = 0; m < 4; ++m)
        #pragma unroll
        for (int n = 0; n < 4; ++n)
          acc[m][n] = __builtin_amdgcn_mfma_f32_16x16x32_bf16(af[m], bf[n], acc[m][n], 0, 0, 0);
    }
    __syncthreads();
  }

  const int orow = brow + wr * 64;
  const int ocol = bcol + wc * 64;
  #pragma unroll
  for (int n = 0; n < 4; ++n) {
    int col = ocol + n * 16 + lrow;
    float b = (col < Nsplit) ? bias0[col] : bias1[col - Nsplit];
    #pragma unroll
    for (int m = 0; m < 4; ++m) {
      #pragma unroll
      for (int r = 0; r < 4; ++r) {
        int row = orow + m * 16 + (lane >> 4) * 4 + r;
        float val = acc[m][n][r] + b;
        if (OUTBF) {
          ((unsigned short*)Cv)[(size_t)row * N + col] = f2bf(val);
        } else {
          ((float*)Cv)[(size_t)row * N + col] = val;
        }
      }
    }
  }
}

// =================== WKV chunked parallel scan ===================
// State (p,a,b) represents A = a*e^p, B = b*e^p with
//   A_t = e^{-w} A_{t-1} + e^{k_t} v_t,  B_t = e^{-w} B_{t-1} + e^{k_t}
//   o_t = (A_{t-1} + e^{u+k_t} v_t) / (B_{t-1} + e^{u+k_t})
// Empty state (p=-1e30, a=b=0) through the uniform step rule reproduces the
// reference init and O[0]=v[0] exactly.

// Pass 1: per-(chunk,channel) local state from empty. idx = [chunk][n][c].
__global__ __launch_bounds__(256) void wkv_chunk_state_kernel(
    const unsigned short* __restrict__ kv,
    const float* __restrict__ wdec,
    float* __restrict__ stP, float* __restrict__ stA, float* __restrict__ stB) {
  int idx = blockIdx.x * 256 + threadIdx.x;
  int c = idx & 1023;
  int n = (idx >> 10) & (NB - 1);
  int chunk = idx >> 13;
  float w = wdec[c];
  const unsigned short* base = kv + (size_t)(n * TSEQ + chunk * LCH) * 2048 + c;
  float p = -1e30f, a = 0.f, b = 0.f;
  #pragma unroll 8
  for (int j = 0; j < LCH; ++j) {
    float kt = bf2f(base[(size_t)j * 2048]);
    float vt = bf2f(base[(size_t)j * 2048 + 1024]);
    float ww2 = p - w;
    float qq2 = fmaxf(ww2, kt);
    float e1 = __expf(ww2 - qq2);
    float e2 = __expf(kt - qq2);
    a = e1 * a + e2 * vt;
    b = e1 * b + e2;
    p = qq2;
  }
  stP[idx] = p; stA[idx] = a; stB[idx] = b;
}

// Pass 2: serial scan over chunks per channel; replaces each chunk state with
// the INCOMING prefix state for that chunk. 8192 threads.
__global__ __launch_bounds__(256) void wkv_scan_kernel(
    const float* __restrict__ wdec,
    float* __restrict__ stP, float* __restrict__ stA, float* __restrict__ stB) {
  int idx = blockIdx.x * 256 + threadIdx.x;   // [n][c]
  int c = idx & 1023;
  float decay = (float)LCH * wdec[c];
  float p = -1e30f, a = 0.f, b = 0.f;
  for (int i = 0; i < CCH; ++i) {
    int off = i * NCHAN + idx;
    float pc = stP[off], ac = stA[off], bc = stB[off];
    stP[off] = p; stA[off] = a; stB[off] = b;   // incoming prefix
    float pd = p - decay;
    float q = fmaxf(pd, pc);
    float e1 = __expf(pd - q);
    float e2 = __expf(pc - q);
    a = e1 * a + e2 * ac;
    b = e1 * b + e2 * bc;
    p = q;
  }
}

// Pass 3: replay each chunk from its incoming prefix, emitting outputs.
__global__ __launch_bounds__(256) void wkv_out_kernel(
    const unsigned short* __restrict__ kv,
    const float* __restrict__ wdec, const float* __restrict__ ubon,
    const float* __restrict__ stP, const float* __restrict__ stA,
    const float* __restrict__ stB,
    unsigned short* __restrict__ O) {
  int idx = blockIdx.x * 256 + threadIdx.x;
  int c = idx & 1023;
  int n = (idx >> 10) & (NB - 1);
  int chunk = idx >> 13;
  float w = wdec[c], u = ubon[c];
  const unsigned short* base = kv + (size_t)(n * TSEQ + chunk * LCH) * 2048 + c;
  unsigned short* ob = O + (size_t)(n * TSEQ + chunk * LCH) * DIMSZ + c;
  float p = stP[idx], a = stA[idx], b = stB[idx];
  #pragma unroll 4
  for (int j = 0; j < LCH; ++j) {
    float kt = bf2f(base[(size_t)j * 2048]);
    float vt = bf2f(base[(size_t)j * 2048 + 1024]);
    // output at t from incoming state (bonus u)
    float ww = u + kt;
    float qq = fmaxf(ww, p);
    float e1 = __expf(p - qq);
    float e2 = __expf(ww - qq);
    float num = e1 * a + e2 * vt;
    float den = e1 * b + e2;
    ob[(size_t)j * DIMSZ] = f2bf(num * __builtin_amdgcn_rcpf(den));
    // state update (decay w)
    float ww2 = p - w;
    float qq2 = fmaxf(ww2, kt);
    float e1b = __expf(ww2 - qq2);
    float e2b = __expf(kt - qq2);
    a = e1b * a + e2b * vt;
    b = e1b * b + e2b;
    p = qq2;
  }
}

extern "C" void kernel_launch(void* const* d_in, const int* in_sizes, int n_in,
                              void* d_out, int out_size, void* d_ws, size_t ws_size,
                              hipStream_t stream) {
  const float* x  = (const float*)d_in[0];
  // d_in[1]=Wq, d_in[2]=bq: unused by the reference forward
  const float* Wk = (const float*)d_in[3];
  const float* bk = (const float*)d_in[4];
  const float* Wv = (const float*)d_in[5];
  const float* bv = (const float*)d_in[6];
  const float* wr = (const float*)d_in[7];
  const float* ur = (const float*)d_in[8];
  const float* Wo = (const float*)d_in[9];
  const float* bo = (const float*)d_in[10];
  float* out = (float*)d_out;

  char* ws = (char*)d_ws;
  unsigned short* xb   = (unsigned short*)(ws);               // 32MB  [16384][1024] bf16 (reused as O)
  unsigned short* WTkv = (unsigned short*)(ws + 33554432);    // 4MB   [2048][1024] bf16 (Wk^T ; Wv^T)
  unsigned short* WoT  = (unsigned short*)(ws + 37748736);    // 2MB   [1024][1024] bf16
  unsigned short* kvb  = (unsigned short*)(ws + 39845888);    // 64MB  [16384][2048] bf16

  // chunk-state scratch lives in d_out (64MB f32): fully overwritten by the
  // final GEMM afterwards, so this is free scratch during the wkv phase.
  float* stP = out;                       // 2MB (CCH*NCHAN floats)
  float* stA = out + CCH * NCHAN;         // 2MB
  float* stB = out + 2 * CCH * NCHAN;     // 2MB

  cast_x_kernel<<<dim3(16384), dim3(256), 0, stream>>>(x, xb);
  transpose_cast_kernel<<<dim3(32, 32), dim3(256), 0, stream>>>(Wk, WTkv);
  transpose_cast_kernel<<<dim3(32, 32), dim3(256), 0, stream>>>(Wv, WTkv + 1024 * 1024);
  transpose_cast_kernel<<<dim3(32, 32), dim3(256), 0, stream>>>(Wo, WoT);

  // k|v projection: [16384][1024] @ [1024][2048] -> bf16 kv buffer (+bk|bv)
  gemm_bt_kernel<1><<<dim3(128, 16), dim3(256), 0, stream>>>(
      xb, WTkv, (void*)kvb, bk, bv, MTOT, 2048, 1024, 1024);

  // WKV chunked scan -> O (bf16) into xb (its x-bf16 contents are consumed)
  wkv_chunk_state_kernel<<<dim3(CCH * NCHAN / 256), dim3(256), 0, stream>>>(
      kvb, wr, stP, stA, stB);
  wkv_scan_kernel<<<dim3(NCHAN / 256), dim3(256), 0, stream>>>(wr, stP, stA, stB);
  wkv_out_kernel<<<dim3(CCH * NCHAN / 256), dim3(256), 0, stream>>>(
      kvb, wr, ur, stP, stA, stB, xb);

  // output projection: [16384][1024] @ [1024][1024] -> f32 d_out (+bo)
  gemm_bt_kernel<0><<<dim3(128, 8), dim3(256), 0, stream>>>(
      xb, WoT, (void*)out, bo, bo, MTOT, 1024, 1024, 1024);
}